// Round 19
// baseline (3918.233 us; speedup 1.0000x reference)
//
#include <hip/hip_runtime.h>
#include <hip/hip_bf16.h>
#include <math.h>

#define DIMD 1024
#define HEADS 16
#define HD 64
#define LAYERS 8
#define HIDDEN 4096
#define VOCAB 266
#define NB 4
#define SEQ 2048
#define ROWS (NB*SEQ)
#define LOG2E 1.4426950408889634f
#define QSCALE (0.125f * LOG2E)
#define BIAS2 (0.01f * LOG2E)
#define THR2 8.0f

typedef float f32x4 __attribute__((ext_vector_type(4)));
typedef float f32x16 __attribute__((ext_vector_type(16)));
typedef __bf16 bf16x8 __attribute__((ext_vector_type(8)));
typedef __bf16 bf16x4 __attribute__((ext_vector_type(4)));

__device__ __forceinline__ f32x16 mfma32(bf16x8 a, bf16x8 b, f32x16 c) {
    return __builtin_amdgcn_mfma_f32_32x32x16_bf16(a, b, c, 0, 0, 0);
}

__device__ __forceinline__ void gload16(const __bf16* g, __bf16* l) {
    __builtin_amdgcn_global_load_lds(
        (const __attribute__((address_space(1))) void*)g,
        (__attribute__((address_space(3))) void*)l, 16, 0, 0);
}

__device__ __forceinline__ unsigned pack2(float a, float b) {
    union { __bf16 h[2]; unsigned u; } t;
    t.h[0] = (__bf16)a; t.h[1] = (__bf16)b;
    return t.u;
}
union PUN8 { unsigned u[4]; bf16x8 v; };

// ---------------- embedding ----------------
__global__ void embed_kernel(const int* __restrict__ tok, const float* __restrict__ te,
                             const float* __restrict__ pe, float* __restrict__ x) {
    int row = blockIdx.x;
    int t = tok[row];
    int l = row & (SEQ - 1);
    int c = threadIdx.x;
    f32x4 tv = *(const f32x4*)(te + (size_t)t * DIMD + c * 4);
    f32x4 pv = *(const f32x4*)(pe + (size_t)l * DIMD + c * 4);
    *(f32x4*)(x + (size_t)row * DIMD + c * 4) = tv + pv;
}

// ---------------- weight convert; w1/wg row-interleaved ----------------
__global__ void cvt_kernel(const float* q, const float* k, const float* v, const float* o,
                           const float* w1, const float* wg, const float* w2,
                           __bf16* __restrict__ dst) {
    const size_t MM = 1024 * 1024;
    const float* src; size_t n; size_t off; int ilv = 0;
    switch (blockIdx.y) {
        case 0: src = q;  n = MM;     off = 0;       break;
        case 1: src = k;  n = MM;     off = MM;      break;
        case 2: src = v;  n = MM;     off = 2 * MM;  break;
        case 3: src = o;  n = MM;     off = 3 * MM;  break;
        case 4: src = w1; n = 4 * MM; off = 4 * MM;  ilv = 1; break;
        case 5: src = wg; n = 4 * MM; off = 4 * MM;  ilv = 2; break;
        default: src = w2; n = 4 * MM; off = 12 * MM; break;
    }
    size_t stride = (size_t)gridDim.x * blockDim.x * 8;
    for (size_t i = ((size_t)blockIdx.x * blockDim.x + threadIdx.x) * 8; i < n; i += stride) {
        f32x4 a = *(const f32x4*)(src + i);
        f32x4 b = *(const f32x4*)(src + i + 4);
        bf16x8 ov;
        ov[0] = (__bf16)a[0]; ov[1] = (__bf16)a[1]; ov[2] = (__bf16)a[2]; ov[3] = (__bf16)a[3];
        ov[4] = (__bf16)b[0]; ov[5] = (__bf16)b[1]; ov[6] = (__bf16)b[2]; ov[7] = (__bf16)b[3];
        size_t di;
        if (ilv) {
            size_t row = i >> 10, col = i & 1023;
            di = off + (((row << 1) | (ilv - 1)) << 10) + col;
        } else {
            di = off + i;
        }
        *(bf16x8*)(dst + di) = ov;
    }
}

// ---------------- LayerNorm ----------------
template<bool F32OUT>
__global__ void ln_kernel(const float* __restrict__ xin, size_t row_stride,
                          const float* __restrict__ g, const float* __restrict__ bb,
                          void* __restrict__ out) {
    int row = blockIdx.x;
    int c = threadIdx.x;
    const float* xr = xin + (size_t)row * row_stride;
    f32x4 v = *(const f32x4*)(xr + c * 4);
    float s = v[0] + v[1] + v[2] + v[3];
    float s2 = v[0]*v[0] + v[1]*v[1] + v[2]*v[2] + v[3]*v[3];
    #pragma unroll
    for (int o = 32; o; o >>= 1) { s += __shfl_xor(s, o); s2 += __shfl_xor(s2, o); }
    __shared__ float red[8];
    int w = c >> 6, lane = c & 63;
    if (lane == 0) { red[w] = s; red[4 + w] = s2; }
    __syncthreads();
    s = red[0] + red[1] + red[2] + red[3];
    s2 = red[4] + red[5] + red[6] + red[7];
    float mean = s * (1.f / DIMD);
    float var = s2 * (1.f / DIMD) - mean * mean;
    float rstd = rsqrtf(var + 1e-5f);
    f32x4 gv = *(const f32x4*)(g + c * 4);
    f32x4 bv = *(const f32x4*)(bb + c * 4);
    f32x4 o4;
    #pragma unroll
    for (int j = 0; j < 4; ++j) o4[j] = (v[j] - mean) * rstd * gv[j] + bv[j];
    if (F32OUT) {
        *(f32x4*)((float*)out + (size_t)row * DIMD + c * 4) = o4;
    } else {
        bf16x4 hv;
        #pragma unroll
        for (int j = 0; j < 4; ++j) hv[j] = (__bf16)o4[j];
        *(bf16x4*)((__bf16*)out + (size_t)row * DIMD + c * 4) = hv;
    }
}

// ---------------- 128x128 GEMM, 32x32x16 MFMA, swizzled LDS, 4 blocks/CU ----------
// mfma32 C layout (m74/m101, HW-verified by attn): M=(r&3)+8*(r>>2)+4*hi, N=lane&31.
// MFMA cycle cut vs 16x16x32: 16x32.5 = 520 vs 32x19.4 = 620 cyc/wave-K-tile (m06/m119).
// launch_bounds (256,4): <=128 VGPR cap; kernel ~64-80. (256,5) spilled (r10).
// EPI 2: f32 residual accumulate; EPI 5: QKV scatter; EPI 6: swiglu interleave
template<int EPI>
__global__ __launch_bounds__(256, 4)
void gemm_bt(const __bf16* __restrict__ A, const __bf16* __restrict__ W,
             int M, int N, int K,
             __bf16* bdst, float* fdst, float scale) {
    __shared__ __bf16 As[128 * 64];
    __shared__ __bf16 Bs[128 * 64];
    int tid = threadIdx.x;
    int lane = tid & 63, w = tid >> 6;
    int wm = w >> 1, wn = w & 1;
    int l32 = lane & 31, hi = lane >> 5;
    int m0 = blockIdx.y * 128, n0 = blockIdx.x * 128;
    f32x16 acc[2][2] = {};
    int trow = tid >> 3;
    int cs8 = ((tid & 7) ^ (trow & 7)) * 8;     // inverse-swizzled source chunk
    const __bf16* ga = A + (size_t)(m0 + trow) * K + cs8;
    const __bf16* gb = W + (size_t)(n0 + trow) * K + cs8;
    int rsw = l32 & 7;                          // read row & 7 (rows are base+l32, base%8==0)

    for (int k0 = 0; k0 < K; k0 += 64) {
        #pragma unroll
        for (int p = 0; p < 4; ++p) {
            gload16(ga + (size_t)(p * 32) * K + k0, As + (p * 256 + w * 64) * 8);
            gload16(gb + (size_t)(p * 32) * K + k0, Bs + (p * 256 + w * 64) * 8);
        }
        __syncthreads();
        #pragma unroll
        for (int kk = 0; kk < 4; ++kk) {
            int ch = ((kk * 2 + hi) ^ rsw) << 4;    // swizzled 16B chunk offset
            bf16x8 af[2], bfv[2];
            #pragma unroll
            for (int mb = 0; mb < 2; ++mb) {
                int ar = wm * 64 + mb * 32 + l32;
                af[mb] = *(const bf16x8*)((const char*)As + ar * 128 + ch);
            }
            #pragma unroll
            for (int nb = 0; nb < 2; ++nb) {
                int br = wn * 64 + nb * 32 + l32;
                bfv[nb] = *(const bf16x8*)((const char*)Bs + br * 128 + ch);
            }
            #pragma unroll
            for (int mb = 0; mb < 2; ++mb)
                #pragma unroll
                for (int nb = 0; nb < 2; ++nb)
                    acc[mb][nb] = mfma32(af[mb], bfv[nb], acc[mb][nb]);
        }
        __syncthreads();
    }

    #pragma unroll
    for (int mb = 0; mb < 2; ++mb) {
        #pragma unroll
        for (int nb = 0; nb < 2; ++nb) {
            int col = n0 + wn * 64 + nb * 32 + l32;
            #pragma unroll
            for (int rq = 0; rq < 4; ++rq) {
                int rbase = m0 + wm * 64 + mb * 32 + 8 * rq + 4 * hi;
                if (EPI == 2) {
                    #pragma unroll
                    for (int j = 0; j < 4; ++j) {
                        size_t idx = (size_t)(rbase + j) * N + col;
                        fdst[idx] += acc[mb][nb][rq * 4 + j];
                    }
                } else if (EPI == 5) {
                    int which = col >> 10;
                    int c = col & 1023;
                    int hh = c >> 6, d = c & 63;
                    if (which == 2) {
                        int b = rbase >> 11, l = rbase & 2047;
                        __bf16* vp = bdst + 2 * (size_t)ROWS * DIMD;
                        bf16x4 hv;
                        #pragma unroll
                        for (int j = 0; j < 4; ++j) hv[j] = (__bf16)acc[mb][nb][rq * 4 + j];
                        *(bf16x4*)(vp + ((size_t)(b * HEADS + hh) * HD + d) * SEQ + l) = hv;
                    } else {
                        float sc = (which == 0) ? scale : 1.f;
                        __bf16* base = bdst + (size_t)which * ROWS * DIMD;
                        #pragma unroll
                        for (int j = 0; j < 4; ++j) {
                            int row = rbase + j;
                            int b = row >> 11, l = row & 2047;
                            base[(((size_t)(b * HEADS + hh) * SEQ + l) << 6) + d] =
                                (__bf16)(acc[mb][nb][rq * 4 + j] * sc);
                        }
                    }
                } else if (EPI == 6) {
                    #pragma unroll
                    for (int j = 0; j < 4; ++j) {
                        float own = acc[mb][nb][rq * 4 + j];
                        float other = __shfl_xor(own, 1);
                        if (!(lane & 1)) {
                            float si = own / (1.f + __expf(-own));
                            bdst[(size_t)(rbase + j) * (N >> 1) + (col >> 1)] = (__bf16)(si * other);
                        }
                    }
                }
            }
        }
    }
}

// ---------------- flash attention: 1 q-tile/block, heavy-first, full-tile fast path ------
// S^T = mfma32(K,Q): col=lane&31=qrow, row=key=(r&3)+8(r>>2)+4*hi (m74/m101 layout).
__global__ __launch_bounds__(256, 2)
void attn_kernel(const __bf16* __restrict__ qt, const __bf16* __restrict__ kt,
                 const __bf16* __restrict__ vt, __bf16* __restrict__ ao) {
    int qtile = 15 - (blockIdx.x >> 6);   // heavy blocks dispatch first
    int g = blockIdx.x & 63;
    int hh = g & 15, b = g >> 4;
    int tid = threadIdx.x, lane = tid & 63, w = tid >> 6;
    int l32 = lane & 31, hi = lane >> 5;

    __shared__ __bf16 Ks[2][64 * 64];
    __shared__ __bf16 Vs[2][64 * 64];

    const __bf16* qbase = qt + (size_t)(b * HEADS + hh) * SEQ * HD;
    const __bf16* kbase = kt + (size_t)(b * HEADS + hh) * SEQ * HD;
    const __bf16* vbase = vt + (size_t)(b * HEADS + hh) * HD * SEQ;  // [d][l]

    int rr = lane >> 3;
    int cs8 = ((lane & 7) ^ rr) * 8;   // inverse-swizzled source chunk

    int qb = qtile * 128;
    int nt = (qb >> 6) + 2;
    int qrow = qb + w * 32 + l32;      // this lane's q-row (same for lane^32)
    int qrmax = qb + w * 32 + 31;
    float fhi = BIAS2 * 4.f * (float)hi;   // loop-invariant bias component

    // Q as B-frags: slice s holds d = s*16 + hi*8 .. +7
    bf16x8 qf[4];
    #pragma unroll
    for (int s = 0; s < 4; ++s)
        qf[s] = *(const bf16x8*)(qbase + (size_t)qrow * HD + s * 16 + hi * 8);

    f32x16 accO[2] = {};               // O^T: col=qrow, row=d (f*32 block)
    float m = -1e30f, lsum = 0.f;

    // prologue: stage tile 0 into buffer 0
    #pragma unroll
    for (int p = 0; p < 2; ++p) {
        int rbse = p * 32 + w * 8;
        gload16(kbase + (size_t)(rbse + rr) * HD + cs8, Ks[0] + rbse * 64);
        gload16(vbase + (size_t)(rbse + rr) * SEQ + cs8, Vs[0] + rbse * 64);
    }
    __syncthreads();

    for (int t = 0; t < nt; ++t) {
        int cur = t & 1;
        int kv0 = t << 6;

        if (t + 1 < nt) {
            int kv1 = kv0 + 64;
            #pragma unroll
            for (int p = 0; p < 2; ++p) {
                int rbse = p * 32 + w * 8;
                gload16(kbase + (size_t)(kv1 + rbse + rr) * HD + cs8, Ks[cur ^ 1] + rbse * 64);
                gload16(vbase + (size_t)(rbse + rr) * SEQ + kv1 + cs8, Vs[cur ^ 1] + rbse * 64);
            }
        }

        if (kv0 <= qrmax) {
            const char* Kb = (const char*)Ks[cur];
            const char* Vb = (const char*)Vs[cur];

            // S^T = K * Q^T   (2 key-blocks x 4 d-slices)
            f32x16 sacc[2] = {};
            __builtin_amdgcn_s_setprio(1);
            #pragma unroll
            for (int kb = 0; kb < 2; ++kb) {
                int row = kb * 32 + l32;
                int rsw = row & 7;
                #pragma unroll
                for (int s = 0; s < 4; ++s) {
                    int cc = s * 2 + hi;
                    bf16x8 kf = *(const bf16x8*)(Kb + row * 128 + ((cc ^ rsw) << 4));
                    sacc[kb] = mfma32(kf, qf[s], sacc[kb]);
                }
            }
            __builtin_amdgcn_s_setprio(0);

            // bias + row max; wave-uniform fast path when whole tile is unmasked
            float fbase = fmaf((float)kv0, BIAS2, fhi);
            float mx = -1e30f;
            if (kv0 + 63 <= qb + w * 32) {
                #pragma unroll
                for (int kb = 0; kb < 2; ++kb)
                    #pragma unroll
                    for (int r = 0; r < 16; ++r) {
                        float v = sacc[kb][r] +
                                  (fbase + BIAS2 * (float)(kb * 32 + (r & 3) + 8 * (r >> 2)));
                        sacc[kb][r] = v;
                        mx = fmaxf(mx, v);
                    }
            } else {
                #pragma unroll
                for (int kb = 0; kb < 2; ++kb)
                    #pragma unroll
                    for (int r = 0; r < 16; ++r) {
                        int koff = kb * 32 + (r & 3) + 8 * (r >> 2) + 4 * hi;
                        float v = sacc[kb][r] +
                                  (fbase + BIAS2 * (float)(kb * 32 + (r & 3) + 8 * (r >> 2)));
                        v = (kv0 + koff <= qrow) ? v : -1e30f;
                        sacc[kb][r] = v;
                        mx = fmaxf(mx, v);
                    }
            }
            mx = fmaxf(mx, __shfl_xor(mx, 32));

            // defer-max rescale
            if (!__all(mx <= m + THR2)) {
                float mnew = fmaxf(m, mx);
                float rs = exp2f(m - mnew);
                m = mnew; lsum *= rs;
                #pragma unroll
                for (int f = 0; f < 2; ++f)
                    #pragma unroll
                    for (int r = 0; r < 16; ++r) accO[f][r] *= rs;
            }

            // exp + in-register P->bf16 B-frags + PV
            #pragma unroll
            for (int kb = 0; kb < 2; ++kb) {
                float p[16];
                #pragma unroll
                for (int r = 0; r < 16; ++r) { p[r] = exp2f(sacc[kb][r] - m); lsum += p[r]; }
                #pragma unroll
                for (int s = 0; s < 2; ++s) {
                    unsigned a0 = pack2(p[s*8+0], p[s*8+1]);
                    unsigned a1 = pack2(p[s*8+2], p[s*8+3]);
                    unsigned b0 = pack2(p[s*8+4], p[s*8+5]);
                    unsigned b1 = pack2(p[s*8+6], p[s*8+7]);
                    unsigned xa0 = (unsigned)__shfl_xor((int)a0, 32);
                    unsigned xa1 = (unsigned)__shfl_xor((int)a1, 32);
                    unsigned xb0 = (unsigned)__shfl_xor((int)b0, 32);
                    unsigned xb1 = (unsigned)__shfl_xor((int)b1, 32);
                    PUN8 pf;
                    pf.u[0] = hi ? xb0 : a0;
                    pf.u[1] = hi ? xb1 : a1;
                    pf.u[2] = hi ? b0  : xa0;
                    pf.u[3] = hi ? b1  : xa1;
                    __builtin_amdgcn_s_setprio(1);
                    #pragma unroll
                    for (int f = 0; f < 2; ++f) {
                        int d = f * 32 + l32;
                        int cc = kb * 4 + s * 2 + hi;
                        bf16x8 vf = *(const bf16x8*)(Vb + d * 128 + ((cc ^ (d & 7)) << 4));
                        accO[f] = mfma32(vf, pf.v, accO[f]);
                    }
                    __builtin_amdgcn_s_setprio(0);
                }
            }
        }
        __syncthreads();   // drains staging vmcnt; next tile ready, old buffer free
    }

    // epilogue: combine partner partial sums; O^T regs -> bf16x4 stores (d contiguous by 4)
    lsum += __shfl_xor(lsum, 32);
    float inv = 1.f / lsum;
    #pragma unroll
    for (int f = 0; f < 2; ++f)
        #pragma unroll
        for (int gI = 0; gI < 4; ++gI) {
            bf16x4 hv;
            #pragma unroll
            for (int j = 0; j < 4; ++j) hv[j] = (__bf16)(accO[f][gI * 4 + j] * inv);
            int d = f * 32 + 8 * gI + 4 * hi;
            *(bf16x4*)(ao + (size_t)(b * SEQ + qrow) * DIMD + hh * HD + d) = hv;
        }
}

// ---------------- LM head ----------------
__global__ void lm_head(const float* __restrict__ last, const float* __restrict__ lw,
                        float* __restrict__ out) {
    int v = blockIdx.x;
    int c = threadIdx.x, lane = c & 63, w = c >> 6;
    f32x4 wv = *(const f32x4*)(lw + (size_t)v * DIMD + c * 4);
    float a[NB];
    #pragma unroll
    for (int b = 0; b < NB; ++b) {
        f32x4 xv = *(const f32x4*)(last + b * DIMD + c * 4);
        a[b] = wv[0]*xv[0] + wv[1]*xv[1] + wv[2]*xv[2] + wv[3]*xv[3];
    }
    #pragma unroll
    for (int o = 32; o; o >>= 1)
        #pragma unroll
        for (int b = 0; b < NB; ++b) a[b] += __shfl_xor(a[b], o);
    __shared__ float red[4][NB];
    if (lane == 0)
        #pragma unroll
        for (int b = 0; b < NB; ++b) red[w][b] = a[b];
    __syncthreads();
    if (c < NB) {
        float s = red[0][c] + red[1][c] + red[2][c] + red[3][c];
        out[c * VOCAB + v] = s;
    }
}

extern "C" void kernel_launch(void* const* d_in, const int* in_sizes, int n_in,
                              void* d_out, int out_size, void* d_ws, size_t ws_size,
                              hipStream_t stream) {
    const int*   tokens  = (const int*)d_in[0];
    const float* tok_emb = (const float*)d_in[1];
    const float* pos_emb = (const float*)d_in[2];
    const float* ln1_g   = (const float*)d_in[3];
    const float* ln1_b   = (const float*)d_in[4];
    const float* q_w     = (const float*)d_in[5];
    const float* k_w     = (const float*)d_in[6];
    const float* v_w     = (const float*)d_in[7];
    const float* o_w     = (const float*)d_in[8];
    const float* ln2_g   = (const float*)d_in[9];
    const float* ln2_b   = (const float*)d_in[10];
    const float* w1_w    = (const float*)d_in[11];
    const float* wg_w    = (const float*)d_in[12];
    const float* w2_w    = (const float*)d_in[13];
    const float* lnf_g   = (const float*)d_in[14];
    const float* lnf_b   = (const float*)d_in[15];
    const float* lm_w    = (const float*)d_in[16];

    const size_t MM = 1024 * 1024;
    char* p = (char*)d_ws;
    __bf16* wbf = (__bf16*)p;          p += 16 * MM * 2;               // 32 MB
    float*  x   = (float*)p;           p += (size_t)ROWS * DIMD * 4;   // 32 MB
    __bf16* h   = (__bf16*)p;          p += (size_t)ROWS * DIMD * 2;   // 16 MB
    __bf16* qt  = (__bf16*)p;          p += (size_t)ROWS * DIMD * 2;   // Q,K,V contiguous
    __bf16* kt  = (__bf16*)p;          p += (size_t)ROWS * DIMD * 2;
    __bf16* vt  = (__bf16*)p;          p += (size_t)ROWS * DIMD * 2;
    __bf16* ao  = (__bf16*)p;          p += (size_t)ROWS * DIMD * 2;
    __bf16* abuf= (__bf16*)p;          p += (size_t)ROWS * HIDDEN * 2; // 64 MB (swiglu out)
    float*  last= (float*)p;           p += NB * DIMD * 4;

    embed_kernel<<<ROWS, 256, 0, stream>>>(tokens, tok_emb, pos_emb, x);

    for (int i = 0; i < LAYERS; ++i) {
        cvt_kernel<<<dim3(256, 7), 256, 0, stream>>>(
            q_w + (size_t)i * MM, k_w + (size_t)i * MM, v_w + (size_t)i * MM, o_w + (size_t)i * MM,
            w1_w + (size_t)i * 4 * MM, wg_w + (size_t)i * 4 * MM, w2_w + (size_t)i * 4 * MM, wbf);
        __bf16* wqkv = wbf;             // q,k,v contiguous, N=3072
        __bf16* wo   = wbf + 3 * MM;
        __bf16* w1g  = wbf + 4 * MM;    // interleaved, N=8192
        __bf16* w2   = wbf + 12 * MM;

        ln_kernel<false><<<ROWS, 256, 0, stream>>>(x, DIMD, ln1_g + i * DIMD, ln1_b + i * DIMD, h);

        gemm_bt<5><<<dim3(24, 64), 256, 0, stream>>>(h, wqkv, ROWS, 3 * DIMD, DIMD, qt, nullptr, QSCALE);

        attn_kernel<<<1024, 256, 0, stream>>>(qt, kt, vt, ao);

        gemm_bt<2><<<dim3(8, 64), 256, 0, stream>>>(ao, wo, ROWS, DIMD, DIMD, nullptr, x, 1.f);

        ln_kernel<false><<<ROWS, 256, 0, stream>>>(x, DIMD, ln2_g + i * DIMD, ln2_b + i * DIMD, h);

        gemm_bt<6><<<dim3(64, 64), 256, 0, stream>>>(h, w1g, ROWS, 2 * HIDDEN, DIMD, abuf, nullptr, 1.f);

        gemm_bt<2><<<dim3(8, 64), 256, 0, stream>>>(abuf, w2, ROWS, DIMD, HIDDEN, nullptr, x, 1.f);
    }

    ln_kernel<true><<<NB, 256, 0, stream>>>(x + (size_t)(SEQ - 1) * DIMD, (size_t)SEQ * DIMD,
                                            lnf_g, lnf_b, last);
    lm_head<<<VOCAB, 256, 0, stream>>>(last, lm_w, (float*)d_out);
}

// Round 20
// 3693.485 us; speedup vs baseline: 1.0608x; 1.0608x over previous
//
#include <hip/hip_runtime.h>
#include <hip/hip_bf16.h>
#include <math.h>

#define DIMD 1024
#define HEADS 16
#define HD 64
#define LAYERS 8
#define HIDDEN 4096
#define VOCAB 266
#define NB 4
#define SEQ 2048
#define ROWS (NB*SEQ)
#define LOG2E 1.4426950408889634f
#define QSCALE (0.125f * LOG2E)
#define BIAS2 (0.01f * LOG2E)
#define THR2 8.0f

typedef float f32x4 __attribute__((ext_vector_type(4)));
typedef float f32x16 __attribute__((ext_vector_type(16)));
typedef __bf16 bf16x8 __attribute__((ext_vector_type(8)));
typedef __bf16 bf16x4 __attribute__((ext_vector_type(4)));

__device__ __forceinline__ f32x4 mfma16(bf16x8 a, bf16x8 b, f32x4 c) {
    return __builtin_amdgcn_mfma_f32_16x16x32_bf16(a, b, c, 0, 0, 0);
}
__device__ __forceinline__ f32x16 mfma32(bf16x8 a, bf16x8 b, f32x16 c) {
    return __builtin_amdgcn_mfma_f32_32x32x16_bf16(a, b, c, 0, 0, 0);
}

__device__ __forceinline__ void gload16(const __bf16* g, __bf16* l) {
    __builtin_amdgcn_global_load_lds(
        (const __attribute__((address_space(1))) void*)g,
        (__attribute__((address_space(3))) void*)l, 16, 0, 0);
}

__device__ __forceinline__ unsigned pack2(float a, float b) {
    union { __bf16 h[2]; unsigned u; } t;
    t.h[0] = (__bf16)a; t.h[1] = (__bf16)b;
    return t.u;
}
union PUN8 { unsigned u[4]; bf16x8 v; };

// ---------------- embedding ----------------
__global__ void embed_kernel(const int* __restrict__ tok, const float* __restrict__ te,
                             const float* __restrict__ pe, float* __restrict__ x) {
    int row = blockIdx.x;
    int t = tok[row];
    int l = row & (SEQ - 1);
    int c = threadIdx.x;
    f32x4 tv = *(const f32x4*)(te + (size_t)t * DIMD + c * 4);
    f32x4 pv = *(const f32x4*)(pe + (size_t)l * DIMD + c * 4);
    *(f32x4*)(x + (size_t)row * DIMD + c * 4) = tv + pv;
}

// ---------------- weight convert; w1/wg row-interleaved ----------------
__global__ void cvt_kernel(const float* q, const float* k, const float* v, const float* o,
                           const float* w1, const float* wg, const float* w2,
                           __bf16* __restrict__ dst) {
    const size_t MM = 1024 * 1024;
    const float* src; size_t n; size_t off; int ilv = 0;
    switch (blockIdx.y) {
        case 0: src = q;  n = MM;     off = 0;       break;
        case 1: src = k;  n = MM;     off = MM;      break;
        case 2: src = v;  n = MM;     off = 2 * MM;  break;
        case 3: src = o;  n = MM;     off = 3 * MM;  break;
        case 4: src = w1; n = 4 * MM; off = 4 * MM;  ilv = 1; break;
        case 5: src = wg; n = 4 * MM; off = 4 * MM;  ilv = 2; break;
        default: src = w2; n = 4 * MM; off = 12 * MM; break;
    }
    size_t stride = (size_t)gridDim.x * blockDim.x * 8;
    for (size_t i = ((size_t)blockIdx.x * blockDim.x + threadIdx.x) * 8; i < n; i += stride) {
        f32x4 a = *(const f32x4*)(src + i);
        f32x4 b = *(const f32x4*)(src + i + 4);
        bf16x8 ov;
        ov[0] = (__bf16)a[0]; ov[1] = (__bf16)a[1]; ov[2] = (__bf16)a[2]; ov[3] = (__bf16)a[3];
        ov[4] = (__bf16)b[0]; ov[5] = (__bf16)b[1]; ov[6] = (__bf16)b[2]; ov[7] = (__bf16)b[3];
        size_t di;
        if (ilv) {
            size_t row = i >> 10, col = i & 1023;
            di = off + (((row << 1) | (ilv - 1)) << 10) + col;
        } else {
            di = off + i;
        }
        *(bf16x8*)(dst + di) = ov;
    }
}

// ---------------- LayerNorm ----------------
template<bool F32OUT>
__global__ void ln_kernel(const float* __restrict__ xin, size_t row_stride,
                          const float* __restrict__ g, const float* __restrict__ bb,
                          void* __restrict__ out) {
    int row = blockIdx.x;
    int c = threadIdx.x;
    const float* xr = xin + (size_t)row * row_stride;
    f32x4 v = *(const f32x4*)(xr + c * 4);
    float s = v[0] + v[1] + v[2] + v[3];
    float s2 = v[0]*v[0] + v[1]*v[1] + v[2]*v[2] + v[3]*v[3];
    #pragma unroll
    for (int o = 32; o; o >>= 1) { s += __shfl_xor(s, o); s2 += __shfl_xor(s2, o); }
    __shared__ float red[8];
    int w = c >> 6, lane = c & 63;
    if (lane == 0) { red[w] = s; red[4 + w] = s2; }
    __syncthreads();
    s = red[0] + red[1] + red[2] + red[3];
    s2 = red[4] + red[5] + red[6] + red[7];
    float mean = s * (1.f / DIMD);
    float var = s2 * (1.f / DIMD) - mean * mean;
    float rstd = rsqrtf(var + 1e-5f);
    f32x4 gv = *(const f32x4*)(g + c * 4);
    f32x4 bv = *(const f32x4*)(bb + c * 4);
    f32x4 o4;
    #pragma unroll
    for (int j = 0; j < 4; ++j) o4[j] = (v[j] - mean) * rstd * gv[j] + bv[j];
    if (F32OUT) {
        *(f32x4*)((float*)out + (size_t)row * DIMD + c * 4) = o4;
    } else {
        bf16x4 hv;
        #pragma unroll
        for (int j = 0; j < 4; ++j) hv[j] = (__bf16)o4[j];
        *(bf16x4*)((__bf16*)out + (size_t)row * DIMD + c * 4) = hv;
    }
}

// ---------------- 128x128 GEMM, 16x16x32 MFMA, swizzled LDS, 4 blocks/CU ----------
// r19 lesson: mfma32's 32-row column read pattern is a 4-way bank conflict under
// any XOR swizzle (rows 0/8/16/24 alias); 16x16x32 stays conflict-free. Keep 16x16.
// launch_bounds (256,4): <=128 VGPR cap; kernel uses 64. (256,5) spilled (r10).
// Split-K + atomicAdd tried r13: regression. 8-phase x4 attempts: all <= this.
// EPI 2: f32 residual accumulate; EPI 5: QKV scatter; EPI 6: swiglu interleave
template<int EPI>
__global__ __launch_bounds__(256, 4)
void gemm_bt(const __bf16* __restrict__ A, const __bf16* __restrict__ W,
             int M, int N, int K,
             __bf16* bdst, float* fdst, float scale) {
    __shared__ __bf16 As[128 * 64];
    __shared__ __bf16 Bs[128 * 64];
    int tid = threadIdx.x;
    int lane = tid & 63, w = tid >> 6;
    int wm = w >> 1, wn = w & 1;
    int g16 = lane >> 4, l16 = lane & 15;
    int m0 = blockIdx.y * 128, n0 = blockIdx.x * 128;
    f32x4 acc[4][4] = {};
    int trow = tid >> 3;
    int cs8 = ((tid & 7) ^ (trow & 7)) * 8;     // inverse-swizzled source chunk
    const __bf16* ga = A + (size_t)(m0 + trow) * K + cs8;
    const __bf16* gb = W + (size_t)(n0 + trow) * K + cs8;
    int xsw = (l16 & 7) << 4;

    for (int k0 = 0; k0 < K; k0 += 64) {
        #pragma unroll
        for (int p = 0; p < 4; ++p) {
            gload16(ga + (size_t)(p * 32) * K + k0, As + (p * 256 + w * 64) * 8);
            gload16(gb + (size_t)(p * 32) * K + k0, Bs + (p * 256 + w * 64) * 8);
        }
        __syncthreads();
        #pragma unroll
        for (int kk = 0; kk < 2; ++kk) {
            bf16x8 af[4], bfv[4];
            #pragma unroll
            for (int f = 0; f < 4; ++f) {
                int ar = wm * 64 + f * 16 + l16;
                int br = wn * 64 + f * 16 + l16;
                af[f]  = *(const bf16x8*)((const char*)As + ((ar * 128 + kk * 64 + g16 * 16) ^ xsw));
                bfv[f] = *(const bf16x8*)((const char*)Bs + ((br * 128 + kk * 64 + g16 * 16) ^ xsw));
            }
            #pragma unroll
            for (int fm = 0; fm < 4; ++fm)
                #pragma unroll
                for (int fn = 0; fn < 4; ++fn)
                    acc[fm][fn] = mfma16(af[fm], bfv[fn], acc[fm][fn]);
        }
        __syncthreads();
    }

    #pragma unroll
    for (int fm = 0; fm < 4; ++fm) {
        int rbase = m0 + wm * 64 + fm * 16 + g16 * 4;
        #pragma unroll
        for (int fn = 0; fn < 4; ++fn) {
            int col = n0 + wn * 64 + fn * 16 + l16;
            if (EPI == 2) {
                #pragma unroll
                for (int j = 0; j < 4; ++j) {
                    size_t idx = (size_t)(rbase + j) * N + col;
                    fdst[idx] += acc[fm][fn][j];
                }
            } else if (EPI == 5) {
                int which = col >> 10;
                int c = col & 1023;
                int hh = c >> 6, d = c & 63;
                if (which == 2) {
                    int b = rbase >> 11, l = rbase & 2047;
                    __bf16* vp = bdst + 2 * (size_t)ROWS * DIMD;
                    bf16x4 hv;
                    #pragma unroll
                    for (int j = 0; j < 4; ++j) hv[j] = (__bf16)acc[fm][fn][j];
                    *(bf16x4*)(vp + ((size_t)(b * HEADS + hh) * HD + d) * SEQ + l) = hv;
                } else {
                    float sc = (which == 0) ? scale : 1.f;
                    __bf16* base = bdst + (size_t)which * ROWS * DIMD;
                    #pragma unroll
                    for (int j = 0; j < 4; ++j) {
                        int row = rbase + j;
                        int b = row >> 11, l = row & 2047;
                        base[(((size_t)(b * HEADS + hh) * SEQ + l) << 6) + d] =
                            (__bf16)(acc[fm][fn][j] * sc);
                    }
                }
            } else if (EPI == 6) {
                #pragma unroll
                for (int j = 0; j < 4; ++j) {
                    float own = acc[fm][fn][j];
                    float other = __shfl_xor(own, 1);
                    if (!(l16 & 1)) {
                        float si = own / (1.f + __expf(-own));
                        bdst[(size_t)(rbase + j) * (N >> 1) + (col >> 1)] = (__bf16)(si * other);
                    }
                }
            }
        }
    }
}

// ---------------- flash attention: 1 q-tile/block, heavy-first, full-tile fast path ------
// S^T = mfma32(K,Q): col=lane&31=qrow, row=key=(r&3)+8(r>>2)+4*hi (m74/m101 layout).
__global__ __launch_bounds__(256, 2)
void attn_kernel(const __bf16* __restrict__ qt, const __bf16* __restrict__ kt,
                 const __bf16* __restrict__ vt, __bf16* __restrict__ ao) {
    int qtile = 15 - (blockIdx.x >> 6);   // heavy blocks dispatch first
    int g = blockIdx.x & 63;
    int hh = g & 15, b = g >> 4;
    int tid = threadIdx.x, lane = tid & 63, w = tid >> 6;
    int l32 = lane & 31, hi = lane >> 5;

    __shared__ __bf16 Ks[2][64 * 64];
    __shared__ __bf16 Vs[2][64 * 64];

    const __bf16* qbase = qt + (size_t)(b * HEADS + hh) * SEQ * HD;
    const __bf16* kbase = kt + (size_t)(b * HEADS + hh) * SEQ * HD;
    const __bf16* vbase = vt + (size_t)(b * HEADS + hh) * HD * SEQ;  // [d][l]

    int rr = lane >> 3;
    int cs8 = ((lane & 7) ^ rr) * 8;   // inverse-swizzled source chunk

    int qb = qtile * 128;
    int nt = (qb >> 6) + 2;
    int qrow = qb + w * 32 + l32;      // this lane's q-row (same for lane^32)
    int qrmax = qb + w * 32 + 31;
    float fhi = BIAS2 * 4.f * (float)hi;   // loop-invariant bias component

    // Q as B-frags: slice s holds d = s*16 + hi*8 .. +7
    bf16x8 qf[4];
    #pragma unroll
    for (int s = 0; s < 4; ++s)
        qf[s] = *(const bf16x8*)(qbase + (size_t)qrow * HD + s * 16 + hi * 8);

    f32x16 accO[2] = {};               // O^T: col=qrow, row=d (f*32 block)
    float m = -1e30f, lsum = 0.f;

    // prologue: stage tile 0 into buffer 0
    #pragma unroll
    for (int p = 0; p < 2; ++p) {
        int rbse = p * 32 + w * 8;
        gload16(kbase + (size_t)(rbse + rr) * HD + cs8, Ks[0] + rbse * 64);
        gload16(vbase + (size_t)(rbse + rr) * SEQ + cs8, Vs[0] + rbse * 64);
    }
    __syncthreads();

    for (int t = 0; t < nt; ++t) {
        int cur = t & 1;
        int kv0 = t << 6;

        if (t + 1 < nt) {
            int kv1 = kv0 + 64;
            #pragma unroll
            for (int p = 0; p < 2; ++p) {
                int rbse = p * 32 + w * 8;
                gload16(kbase + (size_t)(kv1 + rbse + rr) * HD + cs8, Ks[cur ^ 1] + rbse * 64);
                gload16(vbase + (size_t)(rbse + rr) * SEQ + kv1 + cs8, Vs[cur ^ 1] + rbse * 64);
            }
        }

        if (kv0 <= qrmax) {
            const char* Kb = (const char*)Ks[cur];
            const char* Vb = (const char*)Vs[cur];

            // S^T = K * Q^T   (2 key-blocks x 4 d-slices)
            f32x16 sacc[2] = {};
            __builtin_amdgcn_s_setprio(1);
            #pragma unroll
            for (int kb = 0; kb < 2; ++kb) {
                int row = kb * 32 + l32;
                int rsw = row & 7;
                #pragma unroll
                for (int s = 0; s < 4; ++s) {
                    int cc = s * 2 + hi;
                    bf16x8 kf = *(const bf16x8*)(Kb + row * 128 + ((cc ^ rsw) << 4));
                    sacc[kb] = mfma32(kf, qf[s], sacc[kb]);
                }
            }
            __builtin_amdgcn_s_setprio(0);

            // bias + row max; wave-uniform fast path when whole tile is unmasked
            float fbase = fmaf((float)kv0, BIAS2, fhi);
            float mx = -1e30f;
            if (kv0 + 63 <= qb + w * 32) {
                #pragma unroll
                for (int kb = 0; kb < 2; ++kb)
                    #pragma unroll
                    for (int r = 0; r < 16; ++r) {
                        float v = sacc[kb][r] +
                                  (fbase + BIAS2 * (float)(kb * 32 + (r & 3) + 8 * (r >> 2)));
                        sacc[kb][r] = v;
                        mx = fmaxf(mx, v);
                    }
            } else {
                #pragma unroll
                for (int kb = 0; kb < 2; ++kb)
                    #pragma unroll
                    for (int r = 0; r < 16; ++r) {
                        int koff = kb * 32 + (r & 3) + 8 * (r >> 2) + 4 * hi;
                        float v = sacc[kb][r] +
                                  (fbase + BIAS2 * (float)(kb * 32 + (r & 3) + 8 * (r >> 2)));
                        v = (kv0 + koff <= qrow) ? v : -1e30f;
                        sacc[kb][r] = v;
                        mx = fmaxf(mx, v);
                    }
            }
            mx = fmaxf(mx, __shfl_xor(mx, 32));

            // defer-max rescale
            if (!__all(mx <= m + THR2)) {
                float mnew = fmaxf(m, mx);
                float rs = exp2f(m - mnew);
                m = mnew; lsum *= rs;
                #pragma unroll
                for (int f = 0; f < 2; ++f)
                    #pragma unroll
                    for (int r = 0; r < 16; ++r) accO[f][r] *= rs;
            }

            // exp + in-register P->bf16 B-frags + PV
            #pragma unroll
            for (int kb = 0; kb < 2; ++kb) {
                float p[16];
                #pragma unroll
                for (int r = 0; r < 16; ++r) { p[r] = exp2f(sacc[kb][r] - m); lsum += p[r]; }
                #pragma unroll
                for (int s = 0; s < 2; ++s) {
                    unsigned a0 = pack2(p[s*8+0], p[s*8+1]);
                    unsigned a1 = pack2(p[s*8+2], p[s*8+3]);
                    unsigned b0 = pack2(p[s*8+4], p[s*8+5]);
                    unsigned b1 = pack2(p[s*8+6], p[s*8+7]);
                    unsigned xa0 = (unsigned)__shfl_xor((int)a0, 32);
                    unsigned xa1 = (unsigned)__shfl_xor((int)a1, 32);
                    unsigned xb0 = (unsigned)__shfl_xor((int)b0, 32);
                    unsigned xb1 = (unsigned)__shfl_xor((int)b1, 32);
                    PUN8 pf;
                    pf.u[0] = hi ? xb0 : a0;
                    pf.u[1] = hi ? xb1 : a1;
                    pf.u[2] = hi ? b0  : xa0;
                    pf.u[3] = hi ? b1  : xa1;
                    __builtin_amdgcn_s_setprio(1);
                    #pragma unroll
                    for (int f = 0; f < 2; ++f) {
                        int d = f * 32 + l32;
                        int cc = kb * 4 + s * 2 + hi;
                        bf16x8 vf = *(const bf16x8*)(Vb + d * 128 + ((cc ^ (d & 7)) << 4));
                        accO[f] = mfma32(vf, pf.v, accO[f]);
                    }
                    __builtin_amdgcn_s_setprio(0);
                }
            }
        }
        __syncthreads();   // drains staging vmcnt; next tile ready, old buffer free
    }

    // epilogue: combine partner partial sums; O^T regs -> bf16x4 stores (d contiguous by 4)
    lsum += __shfl_xor(lsum, 32);
    float inv = 1.f / lsum;
    #pragma unroll
    for (int f = 0; f < 2; ++f)
        #pragma unroll
        for (int gI = 0; gI < 4; ++gI) {
            bf16x4 hv;
            #pragma unroll
            for (int j = 0; j < 4; ++j) hv[j] = (__bf16)(accO[f][gI * 4 + j] * inv);
            int d = f * 32 + 8 * gI + 4 * hi;
            *(bf16x4*)(ao + (size_t)(b * SEQ + qrow) * DIMD + hh * HD + d) = hv;
        }
}

// ---------------- LM head ----------------
__global__ void lm_head(const float* __restrict__ last, const float* __restrict__ lw,
                        float* __restrict__ out) {
    int v = blockIdx.x;
    int c = threadIdx.x, lane = c & 63, w = c >> 6;
    f32x4 wv = *(const f32x4*)(lw + (size_t)v * DIMD + c * 4);
    float a[NB];
    #pragma unroll
    for (int b = 0; b < NB; ++b) {
        f32x4 xv = *(const f32x4*)(last + b * DIMD + c * 4);
        a[b] = wv[0]*xv[0] + wv[1]*xv[1] + wv[2]*xv[2] + wv[3]*xv[3];
    }
    #pragma unroll
    for (int o = 32; o; o >>= 1)
        #pragma unroll
        for (int b = 0; b < NB; ++b) a[b] += __shfl_xor(a[b], o);
    __shared__ float red[4][NB];
    if (lane == 0)
        #pragma unroll
        for (int b = 0; b < NB; ++b) red[w][b] = a[b];
    __syncthreads();
    if (c < NB) {
        float s = red[0][c] + red[1][c] + red[2][c] + red[3][c];
        out[c * VOCAB + v] = s;
    }
}

extern "C" void kernel_launch(void* const* d_in, const int* in_sizes, int n_in,
                              void* d_out, int out_size, void* d_ws, size_t ws_size,
                              hipStream_t stream) {
    const int*   tokens  = (const int*)d_in[0];
    const float* tok_emb = (const float*)d_in[1];
    const float* pos_emb = (const float*)d_in[2];
    const float* ln1_g   = (const float*)d_in[3];
    const float* ln1_b   = (const float*)d_in[4];
    const float* q_w     = (const float*)d_in[5];
    const float* k_w     = (const float*)d_in[6];
    const float* v_w     = (const float*)d_in[7];
    const float* o_w     = (const float*)d_in[8];
    const float* ln2_g   = (const float*)d_in[9];
    const float* ln2_b   = (const float*)d_in[10];
    const float* w1_w    = (const float*)d_in[11];
    const float* wg_w    = (const float*)d_in[12];
    const float* w2_w    = (const float*)d_in[13];
    const float* lnf_g   = (const float*)d_in[14];
    const float* lnf_b   = (const float*)d_in[15];
    const float* lm_w    = (const float*)d_in[16];

    const size_t MM = 1024 * 1024;
    char* p = (char*)d_ws;
    __bf16* wbf = (__bf16*)p;          p += 16 * MM * 2;               // 32 MB
    float*  x   = (float*)p;           p += (size_t)ROWS * DIMD * 4;   // 32 MB
    __bf16* h   = (__bf16*)p;          p += (size_t)ROWS * DIMD * 2;   // 16 MB
    __bf16* qt  = (__bf16*)p;          p += (size_t)ROWS * DIMD * 2;   // Q,K,V contiguous
    __bf16* kt  = (__bf16*)p;          p += (size_t)ROWS * DIMD * 2;
    __bf16* vt  = (__bf16*)p;          p += (size_t)ROWS * DIMD * 2;
    __bf16* ao  = (__bf16*)p;          p += (size_t)ROWS * DIMD * 2;
    __bf16* abuf= (__bf16*)p;          p += (size_t)ROWS * HIDDEN * 2; // 64 MB (swiglu out)
    float*  last= (float*)p;           p += NB * DIMD * 4;

    embed_kernel<<<ROWS, 256, 0, stream>>>(tokens, tok_emb, pos_emb, x);

    for (int i = 0; i < LAYERS; ++i) {
        cvt_kernel<<<dim3(256, 7), 256, 0, stream>>>(
            q_w + (size_t)i * MM, k_w + (size_t)i * MM, v_w + (size_t)i * MM, o_w + (size_t)i * MM,
            w1_w + (size_t)i * 4 * MM, wg_w + (size_t)i * 4 * MM, w2_w + (size_t)i * 4 * MM, wbf);
        __bf16* wqkv = wbf;             // q,k,v contiguous, N=3072
        __bf16* wo   = wbf + 3 * MM;
        __bf16* w1g  = wbf + 4 * MM;    // interleaved, N=8192
        __bf16* w2   = wbf + 12 * MM;

        ln_kernel<false><<<ROWS, 256, 0, stream>>>(x, DIMD, ln1_g + i * DIMD, ln1_b + i * DIMD, h);

        gemm_bt<5><<<dim3(24, 64), 256, 0, stream>>>(h, wqkv, ROWS, 3 * DIMD, DIMD, qt, nullptr, QSCALE);

        attn_kernel<<<1024, 256, 0, stream>>>(qt, kt, vt, ao);

        gemm_bt<2><<<dim3(8, 64), 256, 0, stream>>>(ao, wo, ROWS, DIMD, DIMD, nullptr, x, 1.f);

        ln_kernel<false><<<ROWS, 256, 0, stream>>>(x, DIMD, ln2_g + i * DIMD, ln2_b + i * DIMD, h);

        gemm_bt<6><<<dim3(64, 64), 256, 0, stream>>>(h, w1g, ROWS, 2 * HIDDEN, DIMD, abuf, nullptr, 1.f);

        gemm_bt<2><<<dim3(8, 64), 256, 0, stream>>>(abuf, w2, ROWS, DIMD, HIDDEN, nullptr, x, 1.f);
    }

    ln_kernel<true><<<NB, 256, 0, stream>>>(x + (size_t)(SEQ - 1) * DIMD, (size_t)SEQ * DIMD,
                                            lnf_g, lnf_b, last);
    lm_head<<<VOCAB, 256, 0, stream>>>(last, lm_w, (float*)d_out);
}